// Round 11
// baseline (465.212 us; speedup 1.0000x reference)
//
#include <hip/hip_runtime.h>
#include <hip/hip_bf16.h>
#include <stdint.h>

// Problem dims (fixed by setup_inputs)
#define T_DIM 2048
#define I_DIM 4096
#define O_DIM 4096
#define R_DIM 16
#define QBLK  32

typedef __bf16 bf16x8 __attribute__((ext_vector_type(8)));
typedef float  floatx4 __attribute__((ext_vector_type(4)));
typedef unsigned short ushort_t;

#define AS1 __attribute__((address_space(1)))
#define AS3 __attribute__((address_space(3)))

__device__ __forceinline__ ushort_t f2bf(float f) {
  unsigned u = __float_as_uint(f);
  u += 0x7FFFu + ((u >> 16) & 1u);   // round-to-nearest-even
  return (ushort_t)(u >> 16);
}

__device__ __forceinline__ float dot4(float4 a, float4 b) {
  return a.x * b.x + a.y * b.y + a.z * b.z + a.w * b.w;
}

// ---------------- k_stream (R13): xb=bf16(x) | wb=dequant(q) -----------
// ~30us measured-by-inference (R10 cross-check) -- near the ~23us floor.
__global__ __launch_bounds__(256) void k_stream(const float* __restrict__ x,
                                                const int* __restrict__ q,
                                                const float* __restrict__ scales,
                                                ushort_t* __restrict__ xb,
                                                ushort_t* __restrict__ wb) {
  const int b = blockIdx.x, tid = threadIdx.x;
  if (b < 512) {                              // ---- prep_x
    const int stride = 512 * 256;
    const int u0 = b * 256 + tid;
    float4 v[4][4];
#pragma unroll
    for (int j = 0; j < 4; ++j) {
      const float4* p = (const float4*)x + (size_t)(u0 + j * stride) * 4;
      v[j][0] = p[0]; v[j][1] = p[1]; v[j][2] = p[2]; v[j][3] = p[3];
    }
#pragma unroll
    for (int j = 0; j < 4; ++j) {
      const size_t u = u0 + (size_t)j * stride;
      union { ushort_t us[16]; uint4 o[2]; } r;
#pragma unroll
      for (int k = 0; k < 4; ++k) {
        r.us[k * 4 + 0] = f2bf(v[j][k].x); r.us[k * 4 + 1] = f2bf(v[j][k].y);
        r.us[k * 4 + 2] = f2bf(v[j][k].z); r.us[k * 4 + 3] = f2bf(v[j][k].w);
      }
      ((uint4*)xb)[u * 2] = r.o[0];
      ((uint4*)xb)[u * 2 + 1] = r.o[1];
    }
    return;
  }
  {                                           // ---- prep_w
    const int stride = 1024 * 256;
    const int u0 = (b - 512) * 256 + tid;
    int4 v[4][4];
    float s[4];
#pragma unroll
    for (int j = 0; j < 4; ++j) {
      const size_t u = u0 + (size_t)j * stride;
      const int4* p = (const int4*)q + u * 4;
      v[j][0] = p[0]; v[j][1] = p[1]; v[j][2] = p[2]; v[j][3] = p[3];
      const size_t e = u * 16;
      s[j] = scales[(e >> 12) * (I_DIM / QBLK) + ((e & 4095) >> 5)];
    }
#pragma unroll
    for (int j = 0; j < 4; ++j) {
      const size_t u = u0 + (size_t)j * stride;
      const float sj = s[j];
      union { ushort_t us[16]; uint4 o[2]; } r;
#pragma unroll
      for (int k = 0; k < 4; ++k) {
        r.us[k * 4 + 0] = f2bf((float)(v[j][k].x - 8) * sj);
        r.us[k * 4 + 1] = f2bf((float)(v[j][k].y - 8) * sj);
        r.us[k * 4 + 2] = f2bf((float)(v[j][k].z - 8) * sj);
        r.us[k * 4 + 3] = f2bf((float)(v[j][k].w - 8) * sj);
      }
      ((uint4*)wb)[u * 2] = r.o[0];
      ((uint4*)wb)[u * 2 + 1] = r.o[1];
    }
  }
}

// ---------------- k_xd (R16): xd = alpha * (x @ down^T) ----------------
// R10 cross-round arithmetic exposed old k_xd at ~110us: 256 blocks =
// 4 waves/CU (12.5% occ) grinding a serial 8-iter barrier loop. R16:
// one block per TOKEN (grid 2048 = 8 blocks/CU, full occupancy), no
// LDS staging -- down (256KB) is L2-hot across every block of an XCD.
// Per thread: 4 x float4 of the x row, 16 dot4s each against down rows;
// wave shuffle (width 64) + 4x16 LDS cross-wave reduce. Floor ~15us
// (512MB of L2-served down reads at ~34 TB/s).
__global__ __launch_bounds__(256) void k_xd(const float* __restrict__ x,
                                            const float* __restrict__ down,
                                            const float* __restrict__ alphap,
                                            float* __restrict__ xd) {
  __shared__ float red[4][16];
  const int t = blockIdx.x;                   // token
  const int tid = threadIdx.x;
  const int lane = tid & 63, wv = tid >> 6;

  float acc[16];
#pragma unroll
  for (int r = 0; r < 16; ++r) acc[r] = 0.f;

  const float4* xrow = (const float4*)(x + (size_t)t * I_DIM);
#pragma unroll
  for (int c = 0; c < 4; ++c) {
    const int k4 = c * 256 + tid;             // float4 index in [0,1024)
    float4 xv = xrow[k4];
#pragma unroll
    for (int r = 0; r < 16; ++r) {
      float4 dv = ((const float4*)(down + (size_t)r * I_DIM))[k4];
      acc[r] += dot4(xv, dv);
    }
  }
#pragma unroll
  for (int r = 0; r < 16; ++r) {
    float v = acc[r];
    v += __shfl_down(v, 32);
    v += __shfl_down(v, 16);
    v += __shfl_down(v, 8);
    v += __shfl_down(v, 4);
    v += __shfl_down(v, 2);
    v += __shfl_down(v, 1);
    if (lane == 0) red[wv][r] = v;
  }
  __syncthreads();
  if (tid < 16) {
    float v = red[0][tid] + red[1][tid] + red[2][tid] + red[3][tid];
    xd[t * 16 + tid] = v * alphap[0];
  }
}

// ======================= main GEMM (R9/R11 verbatim, best: 276.6us) ====
// R15 closed the tiling model: with measured per-CU delivery 4.6/6.0/8.2
// B/cy at 1/2/4 blocks/CU, EVERY tiling of this T=2048 shape lands
// 270-310us (grid size caps blocks/CU for byte-efficient tiles --
// m102's documented N=2048 cliff). GEMM held at its measured best.

#define BK 64
#define NT (I_DIM / BK)        // 64 K-tiles
#define ASZ (128 * BK)         // A tile elems (16KB)
#define BSZ (256 * BK)         // B tile elems (32KB)

__device__ __forceinline__ bf16x8 lds_read16(unsigned addr) {
  bf16x8 d;
  asm volatile("ds_read_b128 %0, %1" : "=v"(d) : "v"(addr));
  return d;
}

__device__ __forceinline__ void stage6(const ushort_t* __restrict__ ga,
                                       const ushort_t* __restrict__ gb,
                                       ushort_t* Ast, ushort_t* Bst, int tid) {
#pragma unroll
  for (int it = 0; it < 2; ++it) {
    const int seg = it * 512 + tid;
    const int r = seg >> 3, cg = (seg & 7) ^ (r & 7);
    __builtin_amdgcn_global_load_lds(
        (const AS1 char*)(ga + (size_t)r * I_DIM + cg * 8),
        (AS3 char*)(Ast + (size_t)seg * 8), 16, 0, 0);
  }
#pragma unroll
  for (int it = 0; it < 4; ++it) {
    const int seg = it * 512 + tid;
    const int r = seg >> 3, cg = (seg & 7) ^ (r & 7);
    __builtin_amdgcn_global_load_lds(
        (const AS1 char*)(gb + (size_t)r * I_DIM + cg * 8),
        (AS3 char*)(Bst + (size_t)seg * 8), 16, 0, 0);
  }
}

template<int VM, bool STG>
__device__ __forceinline__ void ktile(unsigned aB, unsigned bB,
                                      ushort_t* Ast, ushort_t* Bst,
                                      const ushort_t* ga, const ushort_t* gb,
                                      floatx4 (&acc)[4][4], int tid) {
  const int lane = tid & 63, wv = tid >> 6;
  const int quad = lane >> 4, m16 = lane & 15;
  const int wm = wv >> 2, wn = wv & 3;

  if constexpr (STG) stage6(ga, gb, Ast, Bst, tid);

  bf16x8 a0[4], b0[4], a1[4], b1[4];
#pragma unroll
  for (int i = 0; i < 4; ++i) {
    const int m = wm * 64 + i * 16 + m16;
    a0[i] = lds_read16(aB + (unsigned)((m * 8 + (quad ^ (m & 7))) * 16));
  }
#pragma unroll
  for (int i = 0; i < 4; ++i) {
    const int n = wn * 64 + i * 16 + m16;
    b0[i] = lds_read16(bB + (unsigned)((n * 8 + (quad ^ (n & 7))) * 16));
  }
#pragma unroll
  for (int i = 0; i < 4; ++i) {
    const int m = wm * 64 + i * 16 + m16;
    a1[i] = lds_read16(aB + (unsigned)((m * 8 + ((4 + quad) ^ (m & 7))) * 16));
  }
#pragma unroll
  for (int i = 0; i < 4; ++i) {
    const int n = wn * 64 + i * 16 + m16;
    b1[i] = lds_read16(bB + (unsigned)((n * 8 + ((4 + quad) ^ (n & 7))) * 16));
  }
  asm volatile("s_waitcnt lgkmcnt(8)" ::: "memory");
  __builtin_amdgcn_sched_barrier(0);
  __builtin_amdgcn_s_setprio(1);
#pragma unroll
  for (int i = 0; i < 4; ++i)
#pragma unroll
    for (int j = 0; j < 4; ++j)
      acc[i][j] = __builtin_amdgcn_mfma_f32_16x16x32_bf16(a0[i], b0[j], acc[i][j], 0, 0, 0);
  __builtin_amdgcn_s_setprio(0);
  asm volatile("s_waitcnt lgkmcnt(0)" ::: "memory");
  __builtin_amdgcn_sched_barrier(0);
  __builtin_amdgcn_s_setprio(1);
#pragma unroll
  for (int i = 0; i < 4; ++i)
#pragma unroll
    for (int j = 0; j < 4; ++j)
      acc[i][j] = __builtin_amdgcn_mfma_f32_16x16x32_bf16(a1[i], b1[j], acc[i][j], 0, 0, 0);
  __builtin_amdgcn_s_setprio(0);
  if constexpr (VM == 6)      asm volatile("s_waitcnt vmcnt(6)" ::: "memory");
  else if constexpr (VM == 0) asm volatile("s_waitcnt vmcnt(0)" ::: "memory");
  if constexpr (VM >= 0) __builtin_amdgcn_sched_barrier(0);
  __builtin_amdgcn_s_barrier();
}

__global__ __launch_bounds__(512, 2) void k_gemm(const ushort_t* __restrict__ xb,
                                                 const ushort_t* __restrict__ wb,
                                                 const float* __restrict__ bias,
                                                 const float* __restrict__ xd,
                                                 const float* __restrict__ up,
                                                 float* __restrict__ y) {
  __shared__ __align__(16) ushort_t As[3][ASZ];   // 48 KB
  __shared__ __align__(16) ushort_t Bs[3][BSZ];   // 96 KB

  const int tid = threadIdx.x;

  const int id = blockIdx.x;
  const int xcd = id & 7, slot = id >> 3;
  const int bx = xcd * 2 + (slot & 1);      // O tile [0,16)
  const int by = slot >> 1;                 // T tile [0,16)
  const int oT = bx * 256, tT = by * 128;

  const ushort_t* ap = xb + (size_t)tT * I_DIM;
  const ushort_t* bp = wb + (size_t)oT * I_DIM;

  const unsigned aL = (unsigned)(uintptr_t)(AS3 ushort_t*)&As[0][0];
  const unsigned bL = (unsigned)(uintptr_t)(AS3 ushort_t*)&Bs[0][0];
  const unsigned aS0 = aL, aS1 = aL + ASZ * 2, aS2 = aL + ASZ * 4;
  const unsigned bS0 = bL, bS1 = bL + BSZ * 2, bS2 = bL + BSZ * 4;

  floatx4 acc[4][4] = {};

  stage6(ap, bp, As[0], Bs[0], tid);
  stage6(ap + BK, bp + BK, As[1], Bs[1], tid);
  asm volatile("s_waitcnt vmcnt(6)" ::: "memory");
  __builtin_amdgcn_sched_barrier(0);
  __builtin_amdgcn_s_barrier();

  int kc = 2 * BK;
  for (int g = 0; g < 20; ++g) {
    ktile<6, true>(aS0, bS0, As[2], Bs[2], ap + kc, bp + kc, acc, tid); kc += BK;
    ktile<6, true>(aS1, bS1, As[0], Bs[0], ap + kc, bp + kc, acc, tid); kc += BK;
    ktile<6, true>(aS2, bS2, As[1], Bs[1], ap + kc, bp + kc, acc, tid); kc += BK;
  }
  ktile<6, true>(aS0, bS0, As[2], Bs[2], ap + kc, bp + kc, acc, tid); kc += BK;
  ktile<6, true>(aS1, bS1, As[0], Bs[0], ap + kc, bp + kc, acc, tid);
  ktile<0, false>(aS2, bS2, nullptr, nullptr, nullptr, nullptr, acc, tid);
  ktile<-1, false>(aS0, bS0, nullptr, nullptr, nullptr, nullptr, acc, tid);

  // Epilogue: y[t][o] = acc + dot16(xd[t], up[o]) + bias[o]
  const int lane = tid & 63, wv = tid >> 6;
  const int quad = lane >> 4, m16 = lane & 15;
  const int wm = wv >> 2, wn = wv & 3;
#pragma unroll
  for (int im = 0; im < 4; ++im) {
#pragma unroll
    for (int reg = 0; reg < 4; ++reg) {
      const int t = tT + wm * 64 + im * 16 + quad * 4 + reg;
      const float4* xr = (const float4*)(xd + t * 16);
      float4 x0 = xr[0], x1 = xr[1], x2 = xr[2], x3 = xr[3];
#pragma unroll
      for (int in_ = 0; in_ < 4; ++in_) {
        const int o = oT + wn * 64 + in_ * 16 + m16;
        const float4* ur = (const float4*)(up + (size_t)o * R_DIM);
        float lv = dot4(x0, ur[0]) + dot4(x1, ur[1]) +
                   dot4(x2, ur[2]) + dot4(x3, ur[3]);
        y[(size_t)t * O_DIM + o] = acc[im][in_][reg] + lv + bias[o];
      }
    }
  }
}

extern "C" void kernel_launch(void* const* d_in, const int* in_sizes, int n_in,
                              void* d_out, int out_size, void* d_ws, size_t ws_size,
                              hipStream_t stream) {
  const float* x      = (const float*)d_in[0];
  const int*   q      = (const int*)d_in[1];
  const float* scales = (const float*)d_in[2];
  const float* up     = (const float*)d_in[3];
  const float* down   = (const float*)d_in[4];
  const float* alpha  = (const float*)d_in[5];
  const float* bias   = (const float*)d_in[6];
  float* y = (float*)d_out;

  // ws layout: xb bf16 [T,I] (16 MB) | wb bf16 [O,I] (32 MB) | xd f32 [T,16]
  ushort_t* xb = (ushort_t*)d_ws;
  ushort_t* wb = (ushort_t*)((char*)d_ws + (size_t)T_DIM * I_DIM * 2);
  float*    xd = (float*)((char*)d_ws + (size_t)T_DIM * I_DIM * 2 + (size_t)O_DIM * I_DIM * 2);

  hipLaunchKernelGGL(k_stream, dim3(1536), dim3(256), 0, stream,
                     x, q, scales, xb, wb);
  hipLaunchKernelGGL(k_xd, dim3(T_DIM), dim3(256), 0, stream, x, down, alpha, xd);
  hipLaunchKernelGGL(k_gemm, dim3((O_DIM / 256) * (T_DIM / 128)), dim3(512), 0, stream,
                     xb, wb, bias, xd, up, y);
}